// Round 9
// baseline (332.356 us; speedup 1.0000x reference)
//
#include <hip/hip_runtime.h>
#include <math.h>

// NEG_INF = -2^32+1 (rounds to -4294967296.0f in fp32, same as the reference's cast)
#define NEG_INF_F (-4294967295.0f)

typedef float f4 __attribute__((ext_vector_type(4)));

constexpr int B_ = 128;
constexpr int T_ = 8192;
constexpr int U_ = 64;
constexpr int NCHUNK = 16;           // blocks per batch
constexpr int CHUNK  = T_ / NCHUNK;  // 512 rows per block
constexpr int WROWS  = CHUNK / 4;    // 128 rows per wave

// ---------------------------------------------------------------------------
// Single fused kernel (R8 stream structure + last-block merge).
// Each wave owns 128 rows: wave-local masked max/sum, unnormalized accumulate
// over its 32 KB value slab (first 4 loads peeled above the prologue, no
// pre-stream barrier — w_lds strip is wave-private). Cross-wave merge gives
// one block partial. Every block publishes (p, ms), __threadfence()s, then
// does ONE device-scope atomicAdd on its batch counter. The block whose add
// returns NCHUNK-1 (no polling — informed by its own atomic) merges all 16
// partials in fixed order (bitwise-identical to the old k_final) and writes
// the batch's 64 outputs. Counters are zeroed by a 512 B hipMemsetAsync
// before the kernel, so every launch is identical (graph-replay safe).
// ---------------------------------------------------------------------------
__global__ __launch_bounds__(256) void k_fused(const float* __restrict__ align,
                                               const int* __restrict__ mask,
                                               const float* __restrict__ value,
                                               float2* __restrict__ ms,
                                               float* __restrict__ p,
                                               unsigned* __restrict__ cnt,
                                               float* __restrict__ out) {
  const int b     = blockIdx.x / NCHUNK;
  const int chunk = blockIdx.x % NCHUNK;
  const int tid   = threadIdx.x;
  const int wid   = tid >> 6;
  const int lane  = tid & 63;
  const int g     = lane >> 4;   // row-group within wave
  const int s     = lane & 15;   // float4 slot within the 64-float row

  const int t0 = chunk * CHUNK + wid * WROWS;  // wave's first row

  // ---- peel: issue the first 4 value loads before the prologue ----
  const f4* v4 = (const f4*)(value + (size_t)b * T_ * U_) + (size_t)t0 * 16;
  const f4 pvA0 = __builtin_nontemporal_load(&v4[(size_t)(g) * 16 + s]);
  const f4 pvB0 = __builtin_nontemporal_load(&v4[(size_t)(g + 4) * 16 + s]);
  const f4 pvA1 = __builtin_nontemporal_load(&v4[(size_t)(8 + g) * 16 + s]);
  const f4 pvB1 = __builtin_nontemporal_load(&v4[(size_t)(8 + g + 4) * 16 + s]);

  // ---- wave-local masked scores: 2 per lane ----
  const size_t abase = (size_t)b * T_ + t0;
  const float2 av = ((const float2*)(align + abase))[lane];
  const int2   mv = ((const int2*)(mask + abase))[lane];
  const float x0 = mv.x ? av.x : NEG_INF_F;
  const float x1 = mv.y ? av.y : NEG_INF_F;

  float m = fmaxf(x0, x1);
#pragma unroll
  for (int off = 32; off > 0; off >>= 1) m = fmaxf(m, __shfl_xor(m, off));

  const float e0 = __expf(x0 - m);
  const float e1 = __expf(x1 - m);
  float ssum = e0 + e1;
#pragma unroll
  for (int off = 32; off > 0; off >>= 1) ssum += __shfl_xor(ssum, off);

  // ---- stage wave's 128 unnormalized weights in its private LDS strip ----
  __shared__ float w_lds[4 * WROWS];
  ((float2*)(w_lds + wid * WROWS))[lane] = make_float2(e0, e1);
  // no __syncthreads(): strip is wave-private, lgkmcnt orders write->read

  // ---- stream the wave's 32 KB value slab: 2 rows/lane/iter, dual acc ----
  const float* wl = w_lds + wid * WROWS;

  f4 acc0, acc1;
  {
    acc0 = wl[g] * pvA0;
    acc1 = wl[g + 4] * pvB0;
    acc0 += wl[8 + g] * pvA1;
    acc1 += wl[8 + g + 4] * pvB1;
  }
#pragma unroll 4
  for (int it = 2; it < WROWS / 8; ++it) {
    const int r0 = it * 8 + g;
    const float wA = wl[r0];
    const float wB = wl[r0 + 4];
    const f4 vA = __builtin_nontemporal_load(&v4[(size_t)r0 * 16 + s]);
    const f4 vB = __builtin_nontemporal_load(&v4[(size_t)(r0 + 4) * 16 + s]);
    acc0 += wA * vA;
    acc1 += wB * vB;
  }
  f4 acc = acc0 + acc1;

  // ---- reduce the 4 row-groups inside the wave ----
#pragma unroll
  for (int off = 16; off <= 32; off <<= 1) {
    acc.x += __shfl_xor(acc.x, off);
    acc.y += __shfl_xor(acc.y, off);
    acc.z += __shfl_xor(acc.z, off);
    acc.w += __shfl_xor(acc.w, off);
  }

  // ---- cross-wave online-softmax merge -> one block partial ----
  __shared__ f4    s_acc[4][16];   // [wave][f4 slot]
  __shared__ float s_m[4], s_s[4];
  if (g == 0) s_acc[wid][s] = acc;
  if (lane == 0) { s_m[wid] = m; s_s[wid] = ssum; }
  __syncthreads();
  if (wid != 0) return;

  const float m0 = s_m[0], m1 = s_m[1], m2 = s_m[2], m3 = s_m[3];
  const float mb = fmaxf(fmaxf(m0, m1), fmaxf(m2, m3));
  const float c0 = __expf(m0 - mb), c1 = __expf(m1 - mb);
  const float c2 = __expf(m2 - mb), c3 = __expf(m3 - mb);
  const float sb = c0 * s_s[0] + c1 * s_s[1] + c2 * s_s[2] + c3 * s_s[3];
  const float* sa = (const float*)s_acc;  // [4][64]
  const float pb = c0 * sa[lane] + c1 * sa[64 + lane] +
                   c2 * sa[128 + lane] + c3 * sa[192 + lane];

  // ---- publish this block's partial ----
  p[((size_t)b * NCHUNK + chunk) * U_ + lane] = pb;
  if (lane == 0) ms[(size_t)b * NCHUNK + chunk] = make_float2(mb, sb);
  __threadfence();

  // ---- one device-scope atomic arrival; last arriver merges (no polling) ----
  unsigned old = 0;
  if (lane == 0)
    old = __hip_atomic_fetch_add(&cnt[b], 1u,
                                 __ATOMIC_ACQ_REL, __HIP_MEMORY_SCOPE_AGENT);
  old = __shfl(old, 0);
  if (old != NCHUNK - 1) return;
  __threadfence();  // acquire side: order partial reads after the atomic

  // ---- merge all 16 partials in fixed order (bitwise == old k_final) ----
  const float2* msb = ms + (size_t)b * NCHUNK;
  float mj[NCHUNK], sj[NCHUNK];
  float mg = NEG_INF_F;
#pragma unroll
  for (int j = 0; j < NCHUNK; ++j) {
    const float2 v = msb[j];
    mj[j] = v.x; sj[j] = v.y;
    mg = fmaxf(mg, v.x);
  }
  float d = 0.f;
  float ej[NCHUNK];
#pragma unroll
  for (int j = 0; j < NCHUNK; ++j) { ej[j] = __expf(mj[j] - mg); d += sj[j] * ej[j]; }

  const float* pbase = p + (size_t)b * NCHUNK * U_ + lane;
  float num = 0.f;
#pragma unroll
  for (int j = 0; j < NCHUNK; ++j) num += pbase[(size_t)j * U_] * ej[j];

  out[(size_t)b * U_ + lane] = num / d;
}

extern "C" void kernel_launch(void* const* d_in, const int* in_sizes, int n_in,
                              void* d_out, int out_size, void* d_ws, size_t ws_size,
                              hipStream_t stream) {
  const float* align = (const float*)d_in[0];
  const float* value = (const float*)d_in[1];
  const int*   mask  = (const int*)d_in[2];
  float* out = (float*)d_out;

  float*    p   = (float*)d_ws;                              // B*NCHUNK*U = 512 KiB
  float2*   ms  = (float2*)(p + (size_t)B_ * NCHUNK * U_);   // 16 KiB
  unsigned* cnt = (unsigned*)(ms + (size_t)B_ * NCHUNK);     // 512 B

  hipMemsetAsync(cnt, 0, B_ * sizeof(unsigned), stream);
  k_fused<<<B_ * NCHUNK, 256, 0, stream>>>(align, mask, value, ms, p, cnt, out);
}

// Round 10
// 48.142 us; speedup vs baseline: 6.9036x; 6.9036x over previous
//
#include <hip/hip_runtime.h>
#include <math.h>

// NEG_INF = -2^32+1 (rounds to -4294967296.0f in fp32, same as the reference's cast)
#define NEG_INF_F (-4294967295.0f)

typedef float f4 __attribute__((ext_vector_type(4)));

constexpr int B_ = 128;
constexpr int T_ = 8192;
constexpr int U_ = 64;
constexpr int NCHUNK = 16;           // blocks per batch
constexpr int CHUNK  = T_ / NCHUNK;  // 512 rows per block
constexpr int WROWS  = CHUNK / 4;    // 128 rows per wave

// ---------------------------------------------------------------------------
// Flash-style stream kernel (R8 — best: 48.46 µs). Each wave owns 128 rows:
// wave-local masked max/sum, unnormalized accumulate over its 32 KB value
// slab, cross-wave online-softmax merge -> one block partial.
// (1) no barrier before streaming (w_lds strip is wave-private; intra-wave
// LDS ordering via lgkmcnt suffices), (2) first 4 value loads issued BEFORE
// the softmax prologue to hide the ~400-cycle shfl-reduce chain under HBM
// latency.
// NOTE (R7/R9 lesson): do NOT fuse the final merge into this kernel. Any
// agent-scope fence+flag/atomic protocol concurrent with the HBM stream
// collapses throughput ~7x on MI355X (per-XCD L2 writeback thrash).
// ---------------------------------------------------------------------------
__global__ __launch_bounds__(256) void k_stream(const float* __restrict__ align,
                                                const int* __restrict__ mask,
                                                const float* __restrict__ value,
                                                float2* __restrict__ ms,
                                                float* __restrict__ p) {
  const int b     = blockIdx.x / NCHUNK;
  const int chunk = blockIdx.x % NCHUNK;
  const int tid   = threadIdx.x;
  const int wid   = tid >> 6;
  const int lane  = tid & 63;
  const int g     = lane >> 4;   // row-group within wave
  const int s     = lane & 15;   // float4 slot within the 64-float row

  const int t0 = chunk * CHUNK + wid * WROWS;  // wave's first row

  // ---- peel: issue the first 4 value loads before the prologue ----
  const f4* v4 = (const f4*)(value + (size_t)b * T_ * U_) + (size_t)t0 * 16;
  const f4 pvA0 = __builtin_nontemporal_load(&v4[(size_t)(g) * 16 + s]);
  const f4 pvB0 = __builtin_nontemporal_load(&v4[(size_t)(g + 4) * 16 + s]);
  const f4 pvA1 = __builtin_nontemporal_load(&v4[(size_t)(8 + g) * 16 + s]);
  const f4 pvB1 = __builtin_nontemporal_load(&v4[(size_t)(8 + g + 4) * 16 + s]);

  // ---- wave-local masked scores: 2 per lane ----
  const size_t abase = (size_t)b * T_ + t0;
  const float2 av = ((const float2*)(align + abase))[lane];
  const int2   mv = ((const int2*)(mask + abase))[lane];
  const float x0 = mv.x ? av.x : NEG_INF_F;
  const float x1 = mv.y ? av.y : NEG_INF_F;

  float m = fmaxf(x0, x1);
#pragma unroll
  for (int off = 32; off > 0; off >>= 1) m = fmaxf(m, __shfl_xor(m, off));

  const float e0 = __expf(x0 - m);
  const float e1 = __expf(x1 - m);
  float ssum = e0 + e1;
#pragma unroll
  for (int off = 32; off > 0; off >>= 1) ssum += __shfl_xor(ssum, off);

  // ---- stage wave's 128 unnormalized weights in its private LDS strip ----
  __shared__ float w_lds[4 * WROWS];
  ((float2*)(w_lds + wid * WROWS))[lane] = make_float2(e0, e1);
  // no __syncthreads(): strip is wave-private, lgkmcnt orders write->read

  // ---- stream the wave's 32 KB value slab: 2 rows/lane/iter, dual acc ----
  const float* wl = w_lds + wid * WROWS;

  f4 acc0, acc1;
  {
    const int r0 = g;
    acc0 = wl[r0] * pvA0;
    acc1 = wl[r0 + 4] * pvB0;
    const int r1 = 8 + g;
    acc0 += wl[r1] * pvA1;
    acc1 += wl[r1 + 4] * pvB1;
  }
#pragma unroll 4
  for (int it = 2; it < WROWS / 8; ++it) {
    const int r0 = it * 8 + g;
    const float wA = wl[r0];
    const float wB = wl[r0 + 4];
    const f4 vA = __builtin_nontemporal_load(&v4[(size_t)r0 * 16 + s]);
    const f4 vB = __builtin_nontemporal_load(&v4[(size_t)(r0 + 4) * 16 + s]);
    acc0 += wA * vA;
    acc1 += wB * vB;
  }
  f4 acc = acc0 + acc1;

  // ---- reduce the 4 row-groups inside the wave ----
#pragma unroll
  for (int off = 16; off <= 32; off <<= 1) {
    acc.x += __shfl_xor(acc.x, off);
    acc.y += __shfl_xor(acc.y, off);
    acc.z += __shfl_xor(acc.z, off);
    acc.w += __shfl_xor(acc.w, off);
  }

  // ---- cross-wave online-softmax merge -> one block partial ----
  __shared__ f4    s_acc[4][16];   // [wave][f4 slot]
  __shared__ float s_m[4], s_s[4];
  if (g == 0) s_acc[wid][s] = acc;
  if (lane == 0) { s_m[wid] = m; s_s[wid] = ssum; }
  __syncthreads();

  if (wid == 0) {
    const float m0 = s_m[0], m1 = s_m[1], m2 = s_m[2], m3 = s_m[3];
    const float mb = fmaxf(fmaxf(m0, m1), fmaxf(m2, m3));
    const float c0 = __expf(m0 - mb), c1 = __expf(m1 - mb);
    const float c2 = __expf(m2 - mb), c3 = __expf(m3 - mb);
    const float* sa = (const float*)s_acc;  // [4][64]
    const float pb = c0 * sa[lane] + c1 * sa[64 + lane] +
                     c2 * sa[128 + lane] + c3 * sa[192 + lane];
    p[((size_t)b * NCHUNK + chunk) * U_ + lane] = pb;
    if (lane == 0) {
      const float sb = c0 * s_s[0] + c1 * s_s[1] + c2 * s_s[2] + c3 * s_s[3];
      ms[(size_t)b * NCHUNK + chunk] = make_float2(mb, sb);
    }
  }
}

// ---------------------------------------------------------------------------
// Merge 16 block-partials per batch. 128 blocks x 64 threads; thread u owns
// output u. The 16 (m_j,s_j) pairs (128 B) broadcast from L1/L2.
// ---------------------------------------------------------------------------
__global__ __launch_bounds__(64) void k_final(const float2* __restrict__ ms,
                                              const float* __restrict__ p,
                                              float* __restrict__ out) {
  const int b = blockIdx.x;
  const int u = threadIdx.x;

  const float2* msb = ms + (size_t)b * NCHUNK;
  float mj[NCHUNK], sj[NCHUNK];
  float m = NEG_INF_F;
#pragma unroll
  for (int j = 0; j < NCHUNK; ++j) {
    const float2 v = msb[j];
    mj[j] = v.x; sj[j] = v.y;
    m = fmaxf(m, v.x);
  }
  float d = 0.f;
  float ej[NCHUNK];
#pragma unroll
  for (int j = 0; j < NCHUNK; ++j) { ej[j] = __expf(mj[j] - m); d += sj[j] * ej[j]; }

  const float* pb = p + (size_t)b * NCHUNK * U_ + u;
  float num = 0.f;
#pragma unroll
  for (int j = 0; j < NCHUNK; ++j) num += pb[(size_t)j * U_] * ej[j];

  out[(size_t)b * U_ + u] = num / d;
}

extern "C" void kernel_launch(void* const* d_in, const int* in_sizes, int n_in,
                              void* d_out, int out_size, void* d_ws, size_t ws_size,
                              hipStream_t stream) {
  const float* align = (const float*)d_in[0];
  const float* value = (const float*)d_in[1];
  const int*   mask  = (const int*)d_in[2];
  float* out = (float*)d_out;

  float2* ms = (float2*)d_ws;                        // B*NCHUNK float2 = 16 KiB
  float*  p  = (float*)d_ws + 2 * (B_ * NCHUNK);     // B*NCHUNK*U floats = 512 KiB

  k_stream<<<B_ * NCHUNK, 256, 0, stream>>>(align, mask, value, ms, p);
  k_final<<<B_, 64, 0, stream>>>(ms, p, out);
}